// Round 15
// baseline (407.479 us; speedup 1.0000x reference)
//
#include <hip/hip_runtime.h>
#include <math.h>

typedef __attribute__((ext_vector_type(8))) short bf16x8;
typedef __attribute__((ext_vector_type(4))) float f32x4;
typedef unsigned int uint32;

// ---- workspace layout (BYTES) ----
#define OFFB_WT3   0LL           // 1,179,648   : WT3[288][256][8] bf16
#define OFFB_PT    1179648LL     // 74,678,272  : PT padded-transposed feats bf16
#define OFFB_WEFFM 1179648LL     // 3,145,728   : weffM[64][96][256] bf16 (ALIASES PT; written after conv)
#define OFFB_ST    75857920LL    // 69,632,000  : S^T [b][px][c] bf16 per level
#define OFFB_PP    145489920LL   // 3,768,320   : pp (L0 2-slot) f32
#define OFFB_P     150405120LL   // 65,536      : (unused)
#define OFFB_BEFF  150470656LL   // 21,504      : beff f32
#define OFFB_HB    150492160LL   // 34,816      : hb[64][136] f32
// end = 150,526,976 bytes (<= 150,983,680 proven in round 1)

// PT element bases: PT0=0  PT1=27,541,504  PT2=34,766,848  PT3=36,749,312
// ST element bases: ST0=0  ST1=26,214,400  ST2=32,768,000  ST3=34,406,400
// pp float bases:   pp0=0 [16][80][2][256]  pp1=655,360  pp2=819,200  pp3=901,120

__device__ inline unsigned short f2bf(float f) {
    uint32 u = __float_as_uint(f);
    uint32 r = (u + 0x7fffu + ((u >> 16) & 1u)) >> 16;
    return (unsigned short)r;
}

// ---------- prep_w worker: WT3[q][co][j], q=(half*9+tap)*16 + (ci&127)>>3 ----------
__device__ void prep_w_worker(int co, int ci, const float* __restrict__ w,
                              unsigned short* __restrict__ WT3) {
    int half = ci >> 7, cc = ci & 127, c8 = cc >> 3, j = cc & 7;
    const float* src = w + ((size_t)co * 256 + ci) * 9;
#pragma unroll
    for (int tap = 0; tap < 9; ++tap) {
        int q = (half * 9 + tap) * 16 + c8;
        WT3[((size_t)q * 256 + co) * 8 + j] = f2bf(src[tap]);
    }
}

// ---------- pad worker: PT[b][y][x][ci] bf16, zero border ----------
template<int H, int W>
__device__ void pad_worker(int bid, int t, const float* __restrict__ feat,
                           unsigned short* __restrict__ PT, unsigned short* lds) {
    constexpr int WP = W + 2;
    int y = bid % (H + 2), b = bid / (H + 2);
    unsigned short* dst = PT + ((size_t)(b * (H + 2) + y)) * WP * 256;
    if (y == 0 || y == H + 1) {
        for (int e = t; e < WP * 256; e += 256) dst[e] = 0;
        return;
    }
    const float* src = feat + ((size_t)b * 256) * (H * W) + (size_t)(y - 1) * W;
    for (int e = t; e < 256 * W; e += 256) {
        int ci = e / W, x = e - ci * W;
        lds[ci * (W + 1) + x] = f2bf(src[(size_t)ci * H * W + x]);
    }
    __syncthreads();
    for (int e = t; e < WP * 256; e += 256) {
        int x = e >> 8, ci = e & 255;
        dst[e] = (x == 0 || x == W + 1) ? (unsigned short)0 : lds[ci * (W + 1) + x - 1];
    }
}

// ---------- fused prep_w + pad_transpose (all levels) ----------
__global__ __launch_bounds__(256) void prep_pad_kernel(
    const float* __restrict__ conv_w,
    const float* __restrict__ feat0, const float* __restrict__ feat1,
    const float* __restrict__ feat2, const float* __restrict__ feat3,
    unsigned short* __restrict__ WT3, unsigned short* __restrict__ PT)
{
    __shared__ unsigned short lds[256 * 81];
    int bid = blockIdx.x;
    int t = threadIdx.x;
    if (bid < 256)        { prep_w_worker(bid, t, conv_w, WT3); }
    else if (bid < 1568)  { pad_worker<80,80>(bid - 256,  t, feat0, PT,              lds); }
    else if (bid < 2240)  { pad_worker<40,40>(bid - 1568, t, feat1, PT + 27541504LL, lds); }
    else if (bid < 2592)  { pad_worker<20,20>(bid - 2240, t, feat2, PT + 34766848LL, lds); }
    else                  { pad_worker<10,10>(bid - 2592, t, feat3, PT + 36749312LL, lds); }
}

// ---------- conv worker: r13 structure, column-tiled (TW px per block) ----------
template<int H, int W, int TW, int NF, int WL, int NT>
__device__ void conv_worker(int bid, int tid,
    const unsigned short* __restrict__ PT,   // [16][H+2][W+2][256]
    const unsigned short* __restrict__ WT3,  // [288][256][8]
    const float* __restrict__ cbias,
    unsigned short* __restrict__ ST,         // [16][H*W][256] bf16 (px-major)
    float* __restrict__ pp,                  // [16][H][NT][256] f32
    unsigned short* smem)
{
    constexpr int WP = W + 2;
    constexpr int NPX = H * W;
    constexpr int SLOTS = 3 * WL * 16;

    int tile = bid % NT;
    int h = (bid / NT) % H;
    int b = bid / (NT * H);
    int px0 = tile * TW;
    int lane = tid & 63, wv = tid >> 6;      // 8 waves
    int g = lane >> 4, l15 = lane & 15;
    int co0 = wv * 32;

    f32x4 acc[2][NF];
#pragma unroll
    for (int m = 0; m < 2; ++m)
#pragma unroll
        for (int n = 0; n < NF; ++n) acc[m][n] = (f32x4)0.0f;

    const unsigned short* ptrow = PT + (size_t)(b * (H + 2) + h) * WP * 256;

    for (int half = 0; half < 2; ++half) {
        if (half) __syncthreads();
        for (int s = tid; s < SLOTS; s += 512) {
            int r = s / (WL * 16);
            int rem = s - r * (WL * 16);
            int x = rem >> 4, cb = rem & 15;
            int xc = px0 + x;
            if (xc >= WP) xc = WP - 1;
            bf16x8 v = *(const bf16x8*)(ptrow + ((size_t)r * WP + xc) * 256 + half * 128 + cb * 8);
            *(bf16x8*)(smem + (((r * WL + x) * 16) + (cb ^ (x & 15))) * 8) = v;
        }
        __syncthreads();

#pragma unroll
        for (int ky = 0; ky < 3; ++ky) {
#pragma unroll
            for (int kx = 0; kx < 3; ++kx) {
#pragma unroll
                for (int cs = 0; cs < 4; ++cs) {
                    int q = (half * 9 + ky * 3 + kx) * 16 + cs * 4 + g;
                    const unsigned short* ap = WT3 + ((size_t)q * 256 + co0 + l15) * 8;
                    bf16x8 a0 = *(const bf16x8*)(ap);
                    bf16x8 a1 = *(const bf16x8*)(ap + 128);
#pragma unroll
                    for (int nf = 0; nf < NF; ++nf) {
                        int xi = nf * 16 + l15 + kx;
                        bf16x8 bv = *(const bf16x8*)(smem +
                            (((ky * WL + xi) * 16) + ((cs * 4 + g) ^ (xi & 15))) * 8);
                        acc[0][nf] = __builtin_amdgcn_mfma_f32_16x16x32_bf16(a0, bv, acc[0][nf], 0, 0, 0);
                        acc[1][nf] = __builtin_amdgcn_mfma_f32_16x16x32_bf16(a1, bv, acc[1][nf], 0, 0, 0);
                    }
                }
            }
        }
    }

    float cb4[2][4];
#pragma unroll
    for (int m = 0; m < 2; ++m)
#pragma unroll
        for (int j = 0; j < 4; ++j)
            cb4[m][j] = cbias[co0 + m * 16 + g * 4 + j];

    float rs[2][4];
#pragma unroll
    for (int m = 0; m < 2; ++m)
#pragma unroll
        for (int j = 0; j < 4; ++j) rs[m][j] = 0.f;

    __syncthreads();   // smem reuse for transpose
    unsigned short* lds_t = smem;   // [TW][260] shorts

#pragma unroll
    for (int m = 0; m < 2; ++m) {
#pragma unroll
        for (int nf = 0; nf < NF; ++nf) {
            int px = nf * 16 + l15;
            bool ok = (px < TW);
            short4 o;
#pragma unroll
            for (int j = 0; j < 4; ++j) {
                float v = acc[m][nf][j] + cb4[m][j];
                v = v > 0.f ? v : 0.f;
                if (ok) rs[m][j] += v;
                ((short*)&o)[j] = (short)f2bf(v);
            }
            if (ok) *(short4*)(lds_t + px * 260 + co0 + m * 16 + g * 4) = o;
        }
    }
    // pooling partials (deterministic shuffle reduce over l15), per-tile slot
#pragma unroll
    for (int m = 0; m < 2; ++m)
#pragma unroll
        for (int j = 0; j < 4; ++j) {
            float r = rs[m][j];
            r += __shfl_xor(r, 1);
            r += __shfl_xor(r, 2);
            r += __shfl_xor(r, 4);
            r += __shfl_xor(r, 8);
            if (l15 == 0)
                pp[(((size_t)b * H + h) * NT + tile) * 256 + co0 + m * 16 + g * 4 + j] = r;
        }
    __syncthreads();
    // coalesced S^T store: [b][h*W + px0 + px][c]
    unsigned short* strow = ST + ((size_t)b * NPX + (size_t)h * W + px0) * 256;
    for (int e = tid; e < TW * 64; e += 512) {
        int px = e >> 6, c4 = e & 63;
        short4 v = *(const short4*)(lds_t + px * 260 + c4 * 4);
        *(short4*)(strow + (size_t)px * 256 + c4 * 4) = v;
    }
}

// ---------- fused conv (all levels; L0 col-tiled x2) ----------
__global__ __launch_bounds__(512) void conv_all_kernel(
    const unsigned short* __restrict__ PT, const unsigned short* __restrict__ WT3,
    const float* __restrict__ cbias, unsigned short* __restrict__ ST,
    float* __restrict__ pp)
{
    __shared__ unsigned short smem[3 * 52 * 128];  // 39,936 B -> 4 blocks/CU
    int bid = blockIdx.x;
    int tid = threadIdx.x;
    if (bid < 2560) {
        conv_worker<80,80,40,3,52,2>(bid, tid, PT, WT3, cbias, ST, pp, smem);
    } else if (bid < 3200) {
        conv_worker<40,40,40,3,52,1>(bid - 2560, tid, PT + 27541504LL, WT3, cbias,
                                     ST + 26214400LL, pp + 655360, smem);
    } else if (bid < 3520) {
        conv_worker<20,20,20,2,36,1>(bid - 3200, tid, PT + 34766848LL, WT3, cbias,
                                     ST + 32768000LL, pp + 819200, smem);
    } else {
        conv_worker<10,10,10,1,20,1>(bid - 3520, tid, PT + 36749312LL, WT3, cbias,
                                     ST + 34406400LL, pp + 901120, smem);
    }
}

// ---------- fused pool + head stage 1 ----------
__global__ __launch_bounds__(256) void pool_head_kernel(
    const float* __restrict__ pp,
    const float* __restrict__ clsw1, const float* __restrict__ clsb1,
    const float* __restrict__ regw1, const float* __restrict__ regb1,
    const float* __restrict__ lvlw,  const float* __restrict__ lvlb,
    const float* __restrict__ clsfb, const float* __restrict__ regfb,
    float* __restrict__ hb, float* __restrict__ beff)
{
    const int rows_[4] = {160, 40, 20, 10};
    const int base_[4] = {0, 655360, 819200, 901120};
    const float inv_[4] = {1.f / 6400.f, 1.f / 1600.f, 1.f / 400.f, 1.f / 100.f};
    int lvl = blockIdx.x >> 4;
    int b   = blockIdx.x & 15;
    int t   = threadIdx.x;
    __shared__ float pl[256];
    __shared__ float lgl[4];
    __shared__ float attl;

    {
        int rows = rows_[lvl];
        const float* src = pp + base_[lvl] + ((size_t)b * rows) * 256 + t;
        float s = 0.f;
        for (int r = 0; r < rows; ++r) s += src[r * 256];
        pl[t] = s * inv_[lvl];
    }
    __syncthreads();

    float hval = 0.f;
    if (t < 64) {
        float a = clsb1[t];
        const float* wr = clsw1 + t * 256;
        for (int c2 = 0; c2 < 256; ++c2) a = fmaf(pl[c2], wr[c2], a);
        hval = a > 0.f ? a : 0.f;
    } else if (t < 128) {
        int j = t - 64;
        float a = regb1[j];
        const float* wr = regw1 + j * 256;
        for (int c2 = 0; c2 < 256; ++c2) a = fmaf(pl[c2], wr[c2], a);
        hval = a > 0.f ? a : 0.f;
    } else if (t < 132) {
        int j = t - 128;
        float a = lvlb[j];
        const float* wr = lvlw + j * 256;
        for (int c2 = 0; c2 < 256; ++c2) a = fmaf(pl[c2], wr[c2], a);
        lgl[j] = a;
    }
    __syncthreads();
    if (t == 0) {
        float m = fmaxf(fmaxf(lgl[0], lgl[1]), fmaxf(lgl[2], lgl[3]));
        float e0 = expf(lgl[0] - m), e1 = expf(lgl[1] - m);
        float e2 = expf(lgl[2] - m), e3 = expf(lgl[3] - m);
        float se = e0 + e1 + e2 + e3;
        float el = (lvl == 0) ? e0 : (lvl == 1) ? e1 : (lvl == 2) ? e2 : e3;
        attl = el / se;
    }
    __syncthreads();
    float att = attl;

    size_t base = (size_t)(lvl * 16 + b) * 136;
    if (t < 128) hb[base + t] = hval;
    else if (t == 128) hb[base + 128] = att;
    if (t < 84) {
        beff[(lvl * 16 + b) * 84 + t] = att * (t < 80 ? clsfb[t] : regfb[t - 80]);
    }
}

// ---------- head stage 2: weffM[lb][96][256] bf16 (m-major), rows 84..95 zero ----------
__global__ __launch_bounds__(256) void weff2_kernel(
    const float* __restrict__ hb,
    const float* __restrict__ clsw2, const float* __restrict__ clsb2,
    const float* __restrict__ regw2, const float* __restrict__ regb2,
    const float* __restrict__ clsfw, const float* __restrict__ regfw,
    unsigned short* __restrict__ weffM)
{
    int c = blockIdx.x;      // 0..255
    int t = threadIdx.x;
    __shared__ float wlds[84 * 64];
    __shared__ float hcs[64 * 65];
    __shared__ float hrs[64 * 65];
    __shared__ float atts[64];
    __shared__ float cst[84];

    {
        const float4* csrc = (const float4*)(clsw2 + (size_t)c * 80 * 64);
        float4* wd = (float4*)wlds;
        for (int e = t; e < 80 * 16; e += 256) wd[e] = csrc[e];
        const float4* rsrc = (const float4*)(regw2 + (size_t)c * 4 * 64);
        for (int e = t; e < 4 * 16; e += 256) wd[80 * 16 + e] = rsrc[e];
    }
    for (int e = t; e < 64 * 64; e += 256) {
        int lb = e >> 6, j = e & 63;
        hcs[lb * 65 + j] = hb[(size_t)lb * 136 + j];
        hrs[lb * 65 + j] = hb[(size_t)lb * 136 + 64 + j];
    }
    if (t < 64) atts[t] = hb[(size_t)t * 136 + 128];
    if (t < 84) {
        cst[t] = (t < 80) ? (clsb2[(size_t)c * 80 + t] + clsfw[(size_t)t * 256 + c])
                          : (regb2[(size_t)c * 4 + (t - 80)] + regfw[(size_t)(t - 80) * 256 + c]);
    }
    __syncthreads();

    int lb = t & 63;
    int kg0 = t >> 6;
    const float* hc = hcs + lb * 65;
    const float* hr = hrs + lb * 65;
    float att = atts[lb];
    unsigned short* ob = weffM + (size_t)lb * 24576;

    for (int kg = kg0; kg < 21; kg += 4) {
        const float* h = (kg == 20) ? hr : hc;
        const float* wr = wlds + kg * 4 * 64;
        float a0 = 0.f, a1 = 0.f, a2 = 0.f, a3 = 0.f;
#pragma unroll
        for (int j = 0; j < 64; ++j) {
            float hj = h[j];
            a0 = fmaf(hj, wr[j], a0);
            a1 = fmaf(hj, wr[64 + j], a1);
            a2 = fmaf(hj, wr[128 + j], a2);
            a3 = fmaf(hj, wr[192 + j], a3);
        }
        int k = kg * 4;
        ob[(size_t)(k + 0) * 256 + c] = f2bf(att * (cst[k + 0] + a0));
        ob[(size_t)(k + 1) * 256 + c] = f2bf(att * (cst[k + 1] + a1));
        ob[(size_t)(k + 2) * 256 + c] = f2bf(att * (cst[k + 2] + a2));
        ob[(size_t)(k + 3) * 256 + c] = f2bf(att * (cst[k + 3] + a3));
    }
    for (int e = t; e < 64 * 12; e += 256) {
        int lb2 = e / 12, k2 = 84 + (e - lb2 * 12);
        weffM[(size_t)lb2 * 24576 + (size_t)k2 * 256 + c] = 0;
    }
}

// ---------- MFMA epilogue: out[k][px] = weffM[k][c] x S^T[px][c] + beff ----------
__global__ __launch_bounds__(512) void epilogue_mfma_kernel(
    const unsigned short* __restrict__ ST, const unsigned short* __restrict__ weffM,
    const float* __restrict__ beff, float* __restrict__ out)
{
    int bid = blockIdx.x;   // 560 blocks
    int lvl, tiles, rem;
    if (bid < 400)      { lvl = 0; tiles = 25; rem = bid; }
    else if (bid < 512) { lvl = 1; tiles = 7;  rem = bid - 400; }
    else if (bid < 544) { lvl = 2; tiles = 2;  rem = bid - 512; }
    else                { lvl = 3; tiles = 1;  rem = bid - 544; }
    const int npx_[4] = {6400, 1600, 400, 100};
    const long long stb_[4] = {0LL, 26214400LL, 32768000LL, 34406400LL};
    const int cb_[4]  = {0, 8192000, 10240000, 10752000};
    const int rb_[4]  = {10880000, 11289600, 11392000, 11417600};
    int npx  = npx_[lvl];
    int tile = rem % tiles;
    int b    = rem / tiles;
    int lb   = lvl * 16 + b;
    int px0  = tile * 256;

    int tid = threadIdx.x;
    int lane = tid & 63, wv = tid >> 6;   // 8 waves
    int g = lane >> 4, l15 = lane & 15;

    __shared__ unsigned short walds[96 * 256];
    __shared__ unsigned short slds[256 * 32];

    const unsigned short* wsrc = weffM + (size_t)lb * 24576;
    for (int e = tid; e < 96 * 32; e += 512) {
        int row = e >> 5, ch = e & 31;
        bf16x8 v = *(const bf16x8*)(wsrc + (size_t)row * 256 + ch * 8);
        int chp = (ch & 16) | ((ch & 15) ^ (row & 15));
        *(bf16x8*)(walds + row * 256 + chp * 8) = v;
    }

    f32x4 acc[6][2];
#pragma unroll
    for (int m = 0; m < 6; ++m) { acc[m][0] = (f32x4)0.0f; acc[m][1] = (f32x4)0.0f; }

    const unsigned short* stB = ST + stb_[lvl] + ((size_t)b * npx + px0) * 256;

    for (int kk = 0; kk < 8; ++kk) {
        __syncthreads();
        for (int pr = tid; pr < 1024; pr += 512) {
            int px = pr >> 2, e = pr & 3;
            bf16x8 v = *(const bf16x8*)(stB + (size_t)px * 256 + kk * 32 + e * 8);
            *(bf16x8*)(slds + px * 32 + ((e ^ ((px >> 1) & 3)) * 8)) = v;
        }
        __syncthreads();

        bf16x8 af[6];
#pragma unroll
        for (int m = 0; m < 6; ++m) {
            int row = m * 16 + l15;
            int chA = kk * 4 + g;
            int chp = (chA & 16) | ((chA & 15) ^ (row & 15));
            af[m] = *(const bf16x8*)(walds + row * 256 + chp * 8);
        }
#pragma unroll
        for (int nn = 0; nn < 2; ++nn) {
            int px = wv * 32 + nn * 16 + l15;
            bf16x8 bf = *(const bf16x8*)(slds + px * 32 + ((g ^ ((px >> 1) & 3)) * 8));
#pragma unroll
            for (int m = 0; m < 6; ++m)
                acc[m][nn] = __builtin_amdgcn_mfma_f32_16x16x32_bf16(af[m], bf, acc[m][nn], 0, 0, 0);
        }
    }

    const float* lbeff = beff + (size_t)lb * 84;
#pragma unroll
    for (int m = 0; m < 6; ++m) {
#pragma unroll
        for (int nn = 0; nn < 2; ++nn) {
            int px = px0 + wv * 32 + nn * 16 + l15;
            if (px >= npx) continue;
#pragma unroll
            for (int j = 0; j < 4; ++j) {
                int k = m * 16 + g * 4 + j;
                if (k >= 84) continue;
                float v = acc[m][nn][j] + lbeff[k];
                float* op;
                if (k < 80) op = out + cb_[lvl] + ((size_t)b * 80 + k) * npx + px;
                else        op = out + rb_[lvl] + ((size_t)b * 4 + (k - 80)) * npx + px;
                *op = v;
            }
        }
    }
}

extern "C" void kernel_launch(void* const* d_in, const int* in_sizes, int n_in,
                              void* d_out, int out_size, void* d_ws, size_t ws_size,
                              hipStream_t stream) {
    (void)in_sizes; (void)n_in; (void)out_size; (void)ws_size;
    const float* feat0  = (const float*)d_in[0];
    const float* feat1  = (const float*)d_in[1];
    const float* feat2  = (const float*)d_in[2];
    const float* feat3  = (const float*)d_in[3];
    const float* conv_w = (const float*)d_in[4];
    const float* conv_b = (const float*)d_in[5];
    const float* clsw1  = (const float*)d_in[6];
    const float* clsb1  = (const float*)d_in[7];
    const float* clsw2  = (const float*)d_in[8];
    const float* clsb2  = (const float*)d_in[9];
    const float* regw1  = (const float*)d_in[10];
    const float* regb1  = (const float*)d_in[11];
    const float* regw2  = (const float*)d_in[12];
    const float* regb2  = (const float*)d_in[13];
    const float* lvlw   = (const float*)d_in[14];
    const float* lvlb   = (const float*)d_in[15];
    const float* clsfw  = (const float*)d_in[16];
    const float* clsfb  = (const float*)d_in[17];
    const float* regfw  = (const float*)d_in[18];
    const float* regfb  = (const float*)d_in[19];

    char* ws = (char*)d_ws;
    unsigned short* WT3   = (unsigned short*)(ws + OFFB_WT3);
    unsigned short* PT    = (unsigned short*)(ws + OFFB_PT);
    unsigned short* weffM = (unsigned short*)(ws + OFFB_WEFFM);
    unsigned short* ST    = (unsigned short*)(ws + OFFB_ST);
    float*          pp    = (float*)(ws + OFFB_PP);
    float*          beff  = (float*)(ws + OFFB_BEFF);
    float*          hb    = (float*)(ws + OFFB_HB);
    float* out = (float*)d_out;

    // fused prep_w + pad_transpose: 256 + 1312 + 672 + 352 + 192 = 2784 blocks
    hipLaunchKernelGGL(prep_pad_kernel, dim3(2784), dim3(256), 0, stream,
                       conv_w, feat0, feat1, feat2, feat3, WT3, PT);

    // fused conv: 2560 + 640 + 320 + 160 = 3680 blocks
    hipLaunchKernelGGL(conv_all_kernel, dim3(3680), dim3(512), 0, stream,
                       PT, WT3, conv_b, ST, pp);

    hipLaunchKernelGGL(pool_head_kernel, dim3(64), dim3(256), 0, stream, pp,
                       clsw1, clsb1, regw1, regb1, lvlw, lvlb, clsfb, regfb, hb, beff);
    hipLaunchKernelGGL(weff2_kernel, dim3(256), dim3(256), 0, stream, hb,
                       clsw2, clsb2, regw2, regb2, clsfw, regfw, weffM);
    hipLaunchKernelGGL(epilogue_mfma_kernel, dim3(560), dim3(512), 0, stream, ST, weffM, beff, out);
}

// Round 16
// 320.136 us; speedup vs baseline: 1.2728x; 1.2728x over previous
//
#include <hip/hip_runtime.h>
#include <math.h>

typedef __attribute__((ext_vector_type(8))) short bf16x8;
typedef __attribute__((ext_vector_type(4))) float f32x4;
typedef unsigned int uint32;

// ---- workspace layout (BYTES) ----
#define OFFB_WT3   0LL           // 1,179,648   : WT3[288][256][8] bf16
#define OFFB_PT    1179648LL     // 74,678,272  : PT padded-transposed feats bf16
#define OFFB_WEFFM 1179648LL     // 3,145,728   : weffM[64][96][256] bf16 (ALIASES PT; written after conv)
#define OFFB_ST    75857920LL    // 69,632,000  : S^T [b][px][c] bf16 per level
#define OFFB_PP    145489920LL   // 2,457,600   : pp[lvl][b][H][256] f32
#define OFFB_BEFF  150470656LL   // 21,504      : beff f32
#define OFFB_HB    150492160LL   // 34,816      : hb[64][136] f32
// end = 150,526,976 bytes (<= 150,983,680 proven in round 1)

// PT element bases: PT0=0  PT1=27,541,504  PT2=34,766,848  PT3=36,749,312
// ST element bases: ST0=0  ST1=26,214,400  ST2=32,768,000  ST3=34,406,400
// pp float bases:   pp0=0 [16][80][256]  pp1=327,680  pp2=491,520  pp3=573,440

__device__ inline unsigned short f2bf(float f) {
    uint32 u = __float_as_uint(f);
    uint32 r = (u + 0x7fffu + ((u >> 16) & 1u)) >> 16;
    return (unsigned short)r;
}

// ---------- prep_w worker: WT3[q][co][j], q=(half*9+tap)*16 + (ci&127)>>3 ----------
__device__ void prep_w_worker(int co, int ci, const float* __restrict__ w,
                              unsigned short* __restrict__ WT3) {
    int half = ci >> 7, cc = ci & 127, c8 = cc >> 3, j = cc & 7;
    const float* src = w + ((size_t)co * 256 + ci) * 9;
#pragma unroll
    for (int tap = 0; tap < 9; ++tap) {
        int q = (half * 9 + tap) * 16 + c8;
        WT3[((size_t)q * 256 + co) * 8 + j] = f2bf(src[tap]);
    }
}

// ---------- pad worker: PT[b][y][x][ci] bf16, zero border ----------
template<int H, int W>
__device__ void pad_worker(int bid, int t, const float* __restrict__ feat,
                           unsigned short* __restrict__ PT, unsigned short* lds) {
    constexpr int WP = W + 2;
    int y = bid % (H + 2), b = bid / (H + 2);
    unsigned short* dst = PT + ((size_t)(b * (H + 2) + y)) * WP * 256;
    if (y == 0 || y == H + 1) {
        for (int e = t; e < WP * 256; e += 256) dst[e] = 0;
        return;
    }
    const float* src = feat + ((size_t)b * 256) * (H * W) + (size_t)(y - 1) * W;
    for (int e = t; e < 256 * W; e += 256) {
        int ci = e / W, x = e - ci * W;
        lds[ci * (W + 1) + x] = f2bf(src[(size_t)ci * H * W + x]);
    }
    __syncthreads();
    for (int e = t; e < WP * 256; e += 256) {
        int x = e >> 8, ci = e & 255;
        dst[e] = (x == 0 || x == W + 1) ? (unsigned short)0 : lds[ci * (W + 1) + x - 1];
    }
}

// ---------- fused prep_w + pad_transpose (all levels) ----------
__global__ __launch_bounds__(256) void prep_pad_kernel(
    const float* __restrict__ conv_w,
    const float* __restrict__ feat0, const float* __restrict__ feat1,
    const float* __restrict__ feat2, const float* __restrict__ feat3,
    unsigned short* __restrict__ WT3, unsigned short* __restrict__ PT)
{
    __shared__ unsigned short lds[256 * 81];
    int bid = blockIdx.x;
    int t = threadIdx.x;
    if (bid < 256)        { prep_w_worker(bid, t, conv_w, WT3); }
    else if (bid < 1568)  { pad_worker<80,80>(bid - 256,  t, feat0, PT,              lds); }
    else if (bid < 2240)  { pad_worker<40,40>(bid - 1568, t, feat1, PT + 27541504LL, lds); }
    else if (bid < 2592)  { pad_worker<20,20>(bid - 2240, t, feat2, PT + 34766848LL, lds); }
    else                  { pad_worker<10,10>(bid - 2592, t, feat3, PT + 36749312LL, lds); }
}

// ---------- conv worker (r14 body + setprio around MFMA phase) ----------
template<int H, int W, int NF, int WL>
__device__ void conv_worker(int bid, int tid,
    const unsigned short* __restrict__ PT,   // [16][H+2][W+2][256]
    const unsigned short* __restrict__ WT3,  // [288][256][8]
    const float* __restrict__ cbias,
    unsigned short* __restrict__ ST,         // [16][H*W][256] bf16 (px-major)
    float* __restrict__ pp,                  // [16][H][256] f32
    unsigned short* smem)
{
    constexpr int WP = W + 2;
    constexpr int NPX = H * W;
    constexpr int SLOTS = 3 * WL * 16;

    int h = bid % H, b = bid / H;
    int lane = tid & 63, wv = tid >> 6;      // 8 waves
    int g = lane >> 4, l15 = lane & 15;
    int co0 = wv * 32;

    f32x4 acc[2][NF];
#pragma unroll
    for (int m = 0; m < 2; ++m)
#pragma unroll
        for (int n = 0; n < NF; ++n) acc[m][n] = (f32x4)0.0f;

    const unsigned short* ptrow = PT + (size_t)(b * (H + 2) + h) * WP * 256;

    for (int half = 0; half < 2; ++half) {
        if (half) __syncthreads();
        for (int s = tid; s < SLOTS; s += 512) {
            int r = s / (WL * 16);
            int rem = s - r * (WL * 16);
            int x = rem >> 4, cb = rem & 15;
            int xc = x < WP ? x : WP - 1;
            bf16x8 v = *(const bf16x8*)(ptrow + ((size_t)r * WP + xc) * 256 + half * 128 + cb * 8);
            *(bf16x8*)(smem + (((r * WL + x) * 16) + (cb ^ (x & 15))) * 8) = v;
        }
        __syncthreads();

        __builtin_amdgcn_s_setprio(1);
#pragma unroll
        for (int ky = 0; ky < 3; ++ky) {
#pragma unroll
            for (int kx = 0; kx < 3; ++kx) {
#pragma unroll
                for (int cs = 0; cs < 4; ++cs) {
                    int q = (half * 9 + ky * 3 + kx) * 16 + cs * 4 + g;
                    const unsigned short* ap = WT3 + ((size_t)q * 256 + co0 + l15) * 8;
                    bf16x8 a0 = *(const bf16x8*)(ap);
                    bf16x8 a1 = *(const bf16x8*)(ap + 128);
#pragma unroll
                    for (int nf = 0; nf < NF; ++nf) {
                        int xi = nf * 16 + l15 + kx;
                        bf16x8 bv = *(const bf16x8*)(smem +
                            (((ky * WL + xi) * 16) + ((cs * 4 + g) ^ (xi & 15))) * 8);
                        acc[0][nf] = __builtin_amdgcn_mfma_f32_16x16x32_bf16(a0, bv, acc[0][nf], 0, 0, 0);
                        acc[1][nf] = __builtin_amdgcn_mfma_f32_16x16x32_bf16(a1, bv, acc[1][nf], 0, 0, 0);
                    }
                }
            }
        }
        __builtin_amdgcn_s_setprio(0);
    }

    float cb4[2][4];
#pragma unroll
    for (int m = 0; m < 2; ++m)
#pragma unroll
        for (int j = 0; j < 4; ++j)
            cb4[m][j] = cbias[co0 + m * 16 + g * 4 + j];

    float rs[2][4];
#pragma unroll
    for (int m = 0; m < 2; ++m)
#pragma unroll
        for (int j = 0; j < 4; ++j) rs[m][j] = 0.f;

    __syncthreads();   // smem reuse for transpose
    unsigned short* lds_t = smem;   // [W][260] shorts

#pragma unroll
    for (int m = 0; m < 2; ++m) {
#pragma unroll
        for (int nf = 0; nf < NF; ++nf) {
            int px = nf * 16 + l15;
            bool ok = (px < W);
            short4 o;
#pragma unroll
            for (int j = 0; j < 4; ++j) {
                float v = acc[m][nf][j] + cb4[m][j];
                v = v > 0.f ? v : 0.f;
                if (ok) rs[m][j] += v;
                ((short*)&o)[j] = (short)f2bf(v);
            }
            if (ok) *(short4*)(lds_t + px * 260 + co0 + m * 16 + g * 4) = o;
        }
    }
#pragma unroll
    for (int m = 0; m < 2; ++m)
#pragma unroll
        for (int j = 0; j < 4; ++j) {
            float r = rs[m][j];
            r += __shfl_xor(r, 1);
            r += __shfl_xor(r, 2);
            r += __shfl_xor(r, 4);
            r += __shfl_xor(r, 8);
            if (l15 == 0)
                pp[((size_t)b * H + h) * 256 + co0 + m * 16 + g * 4 + j] = r;
        }
    __syncthreads();
    unsigned short* strow = ST + ((size_t)b * NPX + (size_t)h * W) * 256;
    for (int e = tid; e < W * 64; e += 512) {
        int px = e >> 6, c4 = e & 63;
        short4 v = *(const short4*)(lds_t + px * 260 + c4 * 4);
        *(short4*)(strow + (size_t)px * 256 + c4 * 4) = v;
    }
}

// ---------- fused conv (all levels; L0 blocks first, small levels fill drain) ----------
__global__ __launch_bounds__(512) void conv_all_kernel(
    const unsigned short* __restrict__ PT, const unsigned short* __restrict__ WT3,
    const float* __restrict__ cbias, unsigned short* __restrict__ ST,
    float* __restrict__ pp)
{
    __shared__ unsigned short smem[3 * 84 * 128];  // max (L0): 64,512 B
    int bid = blockIdx.x;
    int tid = threadIdx.x;
    if (bid < 1280) {
        conv_worker<80,80,5,84>(bid, tid, PT, WT3, cbias, ST, pp, smem);
    } else if (bid < 1920) {
        conv_worker<40,40,3,52>(bid - 1280, tid, PT + 27541504LL, WT3, cbias,
                                ST + 26214400LL, pp + 327680, smem);
    } else if (bid < 2240) {
        conv_worker<20,20,2,36>(bid - 1920, tid, PT + 34766848LL, WT3, cbias,
                                ST + 32768000LL, pp + 491520, smem);
    } else {
        conv_worker<10,10,1,20>(bid - 2240, tid, PT + 36749312LL, WT3, cbias,
                                ST + 34406400LL, pp + 573440, smem);
    }
}

// ---------- fused pool + head stage 1 (r14 pp layout) ----------
__global__ __launch_bounds__(256) void pool_head_kernel(
    const float* __restrict__ pp,
    const float* __restrict__ clsw1, const float* __restrict__ clsb1,
    const float* __restrict__ regw1, const float* __restrict__ regb1,
    const float* __restrict__ lvlw,  const float* __restrict__ lvlb,
    const float* __restrict__ clsfb, const float* __restrict__ regfb,
    float* __restrict__ hb, float* __restrict__ beff)
{
    const int rows_[4] = {80, 40, 20, 10};
    const int base_[4] = {0, 327680, 491520, 573440};
    const float inv_[4] = {1.f / 6400.f, 1.f / 1600.f, 1.f / 400.f, 1.f / 100.f};
    int lvl = blockIdx.x >> 4;
    int b   = blockIdx.x & 15;
    int t   = threadIdx.x;
    __shared__ float pl[256];
    __shared__ float lgl[4];
    __shared__ float attl;

    {
        int rows = rows_[lvl];
        const float* src = pp + base_[lvl] + ((size_t)b * rows) * 256 + t;
        float s = 0.f;
        for (int r = 0; r < rows; ++r) s += src[r * 256];
        pl[t] = s * inv_[lvl];
    }
    __syncthreads();

    float hval = 0.f;
    if (t < 64) {
        float a = clsb1[t];
        const float* wr = clsw1 + t * 256;
        for (int c2 = 0; c2 < 256; ++c2) a = fmaf(pl[c2], wr[c2], a);
        hval = a > 0.f ? a : 0.f;
    } else if (t < 128) {
        int j = t - 64;
        float a = regb1[j];
        const float* wr = regw1 + j * 256;
        for (int c2 = 0; c2 < 256; ++c2) a = fmaf(pl[c2], wr[c2], a);
        hval = a > 0.f ? a : 0.f;
    } else if (t < 132) {
        int j = t - 128;
        float a = lvlb[j];
        const float* wr = lvlw + j * 256;
        for (int c2 = 0; c2 < 256; ++c2) a = fmaf(pl[c2], wr[c2], a);
        lgl[j] = a;
    }
    __syncthreads();
    if (t == 0) {
        float m = fmaxf(fmaxf(lgl[0], lgl[1]), fmaxf(lgl[2], lgl[3]));
        float e0 = expf(lgl[0] - m), e1 = expf(lgl[1] - m);
        float e2 = expf(lgl[2] - m), e3 = expf(lgl[3] - m);
        float se = e0 + e1 + e2 + e3;
        float el = (lvl == 0) ? e0 : (lvl == 1) ? e1 : (lvl == 2) ? e2 : e3;
        attl = el / se;
    }
    __syncthreads();
    float att = attl;

    size_t base = (size_t)(lvl * 16 + b) * 136;
    if (t < 128) hb[base + t] = hval;
    else if (t == 128) hb[base + 128] = att;
    if (t < 84) {
        beff[(lvl * 16 + b) * 84 + t] = att * (t < 80 ? clsfb[t] : regfb[t - 80]);
    }
}

// ---------- head stage 2: weffM[lb][96][256] bf16 (m-major), rows 84..95 zero ----------
__global__ __launch_bounds__(256) void weff2_kernel(
    const float* __restrict__ hb,
    const float* __restrict__ clsw2, const float* __restrict__ clsb2,
    const float* __restrict__ regw2, const float* __restrict__ regb2,
    const float* __restrict__ clsfw, const float* __restrict__ regfw,
    unsigned short* __restrict__ weffM)
{
    int c = blockIdx.x;      // 0..255
    int t = threadIdx.x;
    __shared__ float wlds[84 * 64];
    __shared__ float hcs[64 * 65];
    __shared__ float hrs[64 * 65];
    __shared__ float atts[64];
    __shared__ float cst[84];

    {
        const float4* csrc = (const float4*)(clsw2 + (size_t)c * 80 * 64);
        float4* wd = (float4*)wlds;
        for (int e = t; e < 80 * 16; e += 256) wd[e] = csrc[e];
        const float4* rsrc = (const float4*)(regw2 + (size_t)c * 4 * 64);
        for (int e = t; e < 4 * 16; e += 256) wd[80 * 16 + e] = rsrc[e];
    }
    for (int e = t; e < 64 * 64; e += 256) {
        int lb = e >> 6, j = e & 63;
        hcs[lb * 65 + j] = hb[(size_t)lb * 136 + j];
        hrs[lb * 65 + j] = hb[(size_t)lb * 136 + 64 + j];
    }
    if (t < 64) atts[t] = hb[(size_t)t * 136 + 128];
    if (t < 84) {
        cst[t] = (t < 80) ? (clsb2[(size_t)c * 80 + t] + clsfw[(size_t)t * 256 + c])
                          : (regb2[(size_t)c * 4 + (t - 80)] + regfw[(size_t)(t - 80) * 256 + c]);
    }
    __syncthreads();

    int lb = t & 63;
    int kg0 = t >> 6;
    const float* hc = hcs + lb * 65;
    const float* hr = hrs + lb * 65;
    float att = atts[lb];
    unsigned short* ob = weffM + (size_t)lb * 24576;

    for (int kg = kg0; kg < 21; kg += 4) {
        const float* h = (kg == 20) ? hr : hc;
        const float* wr = wlds + kg * 4 * 64;
        float a0 = 0.f, a1 = 0.f, a2 = 0.f, a3 = 0.f;
#pragma unroll
        for (int j = 0; j < 64; ++j) {
            float hj = h[j];
            a0 = fmaf(hj, wr[j], a0);
            a1 = fmaf(hj, wr[64 + j], a1);
            a2 = fmaf(hj, wr[128 + j], a2);
            a3 = fmaf(hj, wr[192 + j], a3);
        }
        int k = kg * 4;
        ob[(size_t)(k + 0) * 256 + c] = f2bf(att * (cst[k + 0] + a0));
        ob[(size_t)(k + 1) * 256 + c] = f2bf(att * (cst[k + 1] + a1));
        ob[(size_t)(k + 2) * 256 + c] = f2bf(att * (cst[k + 2] + a2));
        ob[(size_t)(k + 3) * 256 + c] = f2bf(att * (cst[k + 3] + a3));
    }
    for (int e = t; e < 64 * 12; e += 256) {
        int lb2 = e / 12, k2 = 84 + (e - lb2 * 12);
        weffM[(size_t)lb2 * 24576 + (size_t)k2 * 256 + c] = 0;
    }
}

// ---------- MFMA epilogue (+ setprio around MFMA cluster) ----------
__global__ __launch_bounds__(512) void epilogue_mfma_kernel(
    const unsigned short* __restrict__ ST, const unsigned short* __restrict__ weffM,
    const float* __restrict__ beff, float* __restrict__ out)
{
    int bid = blockIdx.x;   // 560 blocks
    int lvl, tiles, rem;
    if (bid < 400)      { lvl = 0; tiles = 25; rem = bid; }
    else if (bid < 512) { lvl = 1; tiles = 7;  rem = bid - 400; }
    else if (bid < 544) { lvl = 2; tiles = 2;  rem = bid - 512; }
    else                { lvl = 3; tiles = 1;  rem = bid - 544; }
    const int npx_[4] = {6400, 1600, 400, 100};
    const long long stb_[4] = {0LL, 26214400LL, 32768000LL, 34406400LL};
    const int cb_[4]  = {0, 8192000, 10240000, 10752000};
    const int rb_[4]  = {10880000, 11289600, 11392000, 11417600};
    int npx  = npx_[lvl];
    int tile = rem % tiles;
    int b    = rem / tiles;
    int lb   = lvl * 16 + b;
    int px0  = tile * 256;

    int tid = threadIdx.x;
    int lane = tid & 63, wv = tid >> 6;   // 8 waves
    int g = lane >> 4, l15 = lane & 15;

    __shared__ unsigned short walds[96 * 256];
    __shared__ unsigned short slds[256 * 32];

    const unsigned short* wsrc = weffM + (size_t)lb * 24576;
    for (int e = tid; e < 96 * 32; e += 512) {
        int row = e >> 5, ch = e & 31;
        bf16x8 v = *(const bf16x8*)(wsrc + (size_t)row * 256 + ch * 8);
        int chp = (ch & 16) | ((ch & 15) ^ (row & 15));
        *(bf16x8*)(walds + row * 256 + chp * 8) = v;
    }

    f32x4 acc[6][2];
#pragma unroll
    for (int m = 0; m < 6; ++m) { acc[m][0] = (f32x4)0.0f; acc[m][1] = (f32x4)0.0f; }

    const unsigned short* stB = ST + stb_[lvl] + ((size_t)b * npx + px0) * 256;

    for (int kk = 0; kk < 8; ++kk) {
        __syncthreads();
        for (int pr = tid; pr < 1024; pr += 512) {
            int px = pr >> 2, e = pr & 3;
            bf16x8 v = *(const bf16x8*)(stB + (size_t)px * 256 + kk * 32 + e * 8);
            *(bf16x8*)(slds + px * 32 + ((e ^ ((px >> 1) & 3)) * 8)) = v;
        }
        __syncthreads();

        __builtin_amdgcn_s_setprio(1);
        bf16x8 af[6];
#pragma unroll
        for (int m = 0; m < 6; ++m) {
            int row = m * 16 + l15;
            int chA = kk * 4 + g;
            int chp = (chA & 16) | ((chA & 15) ^ (row & 15));
            af[m] = *(const bf16x8*)(walds + row * 256 + chp * 8);
        }
#pragma unroll
        for (int nn = 0; nn < 2; ++nn) {
            int px = wv * 32 + nn * 16 + l15;
            bf16x8 bf = *(const bf16x8*)(slds + px * 32 + ((g ^ ((px >> 1) & 3)) * 8));
#pragma unroll
            for (int m = 0; m < 6; ++m)
                acc[m][nn] = __builtin_amdgcn_mfma_f32_16x16x32_bf16(af[m], bf, acc[m][nn], 0, 0, 0);
        }
        __builtin_amdgcn_s_setprio(0);
    }

    const float* lbeff = beff + (size_t)lb * 84;
#pragma unroll
    for (int m = 0; m < 6; ++m) {
#pragma unroll
        for (int nn = 0; nn < 2; ++nn) {
            int px = px0 + wv * 32 + nn * 16 + l15;
            if (px >= npx) continue;
#pragma unroll
            for (int j = 0; j < 4; ++j) {
                int k = m * 16 + g * 4 + j;
                if (k >= 84) continue;
                float v = acc[m][nn][j] + lbeff[k];
                float* op;
                if (k < 80) op = out + cb_[lvl] + ((size_t)b * 80 + k) * npx + px;
                else        op = out + rb_[lvl] + ((size_t)b * 4 + (k - 80)) * npx + px;
                *op = v;
            }
        }
    }
}

extern "C" void kernel_launch(void* const* d_in, const int* in_sizes, int n_in,
                              void* d_out, int out_size, void* d_ws, size_t ws_size,
                              hipStream_t stream) {
    (void)in_sizes; (void)n_in; (void)out_size; (void)ws_size;
    const float* feat0  = (const float*)d_in[0];
    const float* feat1  = (const float*)d_in[1];
    const float* feat2  = (const float*)d_in[2];
    const float* feat3  = (const float*)d_in[3];
    const float* conv_w = (const float*)d_in[4];
    const float* conv_b = (const float*)d_in[5];
    const float* clsw1  = (const float*)d_in[6];
    const float* clsb1  = (const float*)d_in[7];
    const float* clsw2  = (const float*)d_in[8];
    const float* clsb2  = (const float*)d_in[9];
    const float* regw1  = (const float*)d_in[10];
    const float* regb1  = (const float*)d_in[11];
    const float* regw2  = (const float*)d_in[12];
    const float* regb2  = (const float*)d_in[13];
    const float* lvlw   = (const float*)d_in[14];
    const float* lvlb   = (const float*)d_in[15];
    const float* clsfw  = (const float*)d_in[16];
    const float* clsfb  = (const float*)d_in[17];
    const float* regfw  = (const float*)d_in[18];
    const float* regfb  = (const float*)d_in[19];

    char* ws = (char*)d_ws;
    unsigned short* WT3   = (unsigned short*)(ws + OFFB_WT3);
    unsigned short* PT    = (unsigned short*)(ws + OFFB_PT);
    unsigned short* weffM = (unsigned short*)(ws + OFFB_WEFFM);
    unsigned short* ST    = (unsigned short*)(ws + OFFB_ST);
    float*          pp    = (float*)(ws + OFFB_PP);
    float*          beff  = (float*)(ws + OFFB_BEFF);
    float*          hb    = (float*)(ws + OFFB_HB);
    float* out = (float*)d_out;

    // fused prep_w + pad_transpose: 256 + 1312 + 672 + 352 + 192 = 2784 blocks
    hipLaunchKernelGGL(prep_pad_kernel, dim3(2784), dim3(256), 0, stream,
                       conv_w, feat0, feat1, feat2, feat3, WT3, PT);

    // fused conv: 1280 + 640 + 320 + 160 = 2400 blocks (r14-proven config)
    hipLaunchKernelGGL(conv_all_kernel, dim3(2400), dim3(512), 0, stream,
                       PT, WT3, conv_b, ST, pp);

    hipLaunchKernelGGL(pool_head_kernel, dim3(64), dim3(256), 0, stream, pp,
                       clsw1, clsb1, regw1, regb1, lvlw, lvlb, clsfb, regfb, hb, beff);
    hipLaunchKernelGGL(weff2_kernel, dim3(256), dim3(256), 0, stream, hb,
                       clsw2, clsb2, regw2, regb2, clsfw, regfw, weffM);
    hipLaunchKernelGGL(epilogue_mfma_kernel, dim3(560), dim3(512), 0, stream, ST, weffM, beff, out);
}

// Round 17
// 308.550 us; speedup vs baseline: 1.3206x; 1.0376x over previous
//
#include <hip/hip_runtime.h>
#include <math.h>

typedef __attribute__((ext_vector_type(8))) short bf16x8;
typedef __attribute__((ext_vector_type(4))) float f32x4;
typedef unsigned int uint32;

// ---- workspace layout (BYTES) ----
#define OFFB_WT3   0LL           // 1,179,648   : WT3[288][256][8] bf16
#define OFFB_PT    1179648LL     // 74,678,272  : PT padded-transposed feats bf16
#define OFFB_WEFFM 1179648LL     // 3,145,728   : weffM[64][96][256] bf16 (ALIASES PT; written after conv)
#define OFFB_ST    75857920LL    // 69,632,000  : S^T [b][px][c] bf16 per level
#define OFFB_PP    145489920LL   // 2,457,600   : pp[lvl][b][H][256] f32
#define OFFB_BEFF  150470656LL   // 21,504      : beff f32
#define OFFB_HB    150492160LL   // 34,816      : hb[64][136] f32
// end = 150,526,976 bytes (<= 150,983,680 proven in round 1)

// PT element bases: PT0=0  PT1=27,541,504  PT2=34,766,848  PT3=36,749,312
// ST element bases: ST0=0  ST1=26,214,400  ST2=32,768,000  ST3=34,406,400
// pp float bases:   pp0=0 [16][80][256]  pp1=327,680  pp2=491,520  pp3=573,440

__device__ inline unsigned short f2bf(float f) {
    uint32 u = __float_as_uint(f);
    uint32 r = (u + 0x7fffu + ((u >> 16) & 1u)) >> 16;
    return (unsigned short)r;
}

// XCD-chunked bijective swizzle (segment size N must be %8==0)
__device__ inline int xcd_swz(int bid, int N) {
    return (bid & 7) * (N >> 3) + (bid >> 3);
}

// ---------- prep_w worker: WT3[q][co][j], q=(half*9+tap)*16 + (ci&127)>>3 ----------
__device__ void prep_w_worker(int co, int ci, const float* __restrict__ w,
                              unsigned short* __restrict__ WT3) {
    int half = ci >> 7, cc = ci & 127, c8 = cc >> 3, j = cc & 7;
    const float* src = w + ((size_t)co * 256 + ci) * 9;
#pragma unroll
    for (int tap = 0; tap < 9; ++tap) {
        int q = (half * 9 + tap) * 16 + c8;
        WT3[((size_t)q * 256 + co) * 8 + j] = f2bf(src[tap]);
    }
}

// ---------- pad worker: PT[b][y][x][ci] bf16, zero border ----------
template<int H, int W>
__device__ void pad_worker(int bid, int t, const float* __restrict__ feat,
                           unsigned short* __restrict__ PT, unsigned short* lds) {
    constexpr int WP = W + 2;
    int y = bid % (H + 2), b = bid / (H + 2);
    unsigned short* dst = PT + ((size_t)(b * (H + 2) + y)) * WP * 256;
    if (y == 0 || y == H + 1) {
        for (int e = t; e < WP * 256; e += 256) dst[e] = 0;
        return;
    }
    const float* src = feat + ((size_t)b * 256) * (H * W) + (size_t)(y - 1) * W;
    for (int e = t; e < 256 * W; e += 256) {
        int ci = e / W, x = e - ci * W;
        lds[ci * (W + 1) + x] = f2bf(src[(size_t)ci * H * W + x]);
    }
    __syncthreads();
    for (int e = t; e < WP * 256; e += 256) {
        int x = e >> 8, ci = e & 255;
        dst[e] = (x == 0 || x == W + 1) ? (unsigned short)0 : lds[ci * (W + 1) + x - 1];
    }
}

// ---------- fused prep_w + pad_transpose (all levels) ----------
__global__ __launch_bounds__(256) void prep_pad_kernel(
    const float* __restrict__ conv_w,
    const float* __restrict__ feat0, const float* __restrict__ feat1,
    const float* __restrict__ feat2, const float* __restrict__ feat3,
    unsigned short* __restrict__ WT3, unsigned short* __restrict__ PT)
{
    __shared__ unsigned short lds[256 * 81];
    int bid = blockIdx.x;
    int t = threadIdx.x;
    if (bid < 256)        { prep_w_worker(bid, t, conv_w, WT3); }
    else if (bid < 1568)  { pad_worker<80,80>(bid - 256,  t, feat0, PT,              lds); }
    else if (bid < 2240)  { pad_worker<40,40>(bid - 1568, t, feat1, PT + 27541504LL, lds); }
    else if (bid < 2592)  { pad_worker<20,20>(bid - 2240, t, feat2, PT + 34766848LL, lds); }
    else                  { pad_worker<10,10>(bid - 2592, t, feat3, PT + 36749312LL, lds); }
}

// ---------- conv worker (r14 body + setprio around MFMA phase) ----------
template<int H, int W, int NF, int WL>
__device__ void conv_worker(int bid, int tid,
    const unsigned short* __restrict__ PT,   // [16][H+2][W+2][256]
    const unsigned short* __restrict__ WT3,  // [288][256][8]
    const float* __restrict__ cbias,
    unsigned short* __restrict__ ST,         // [16][H*W][256] bf16 (px-major)
    float* __restrict__ pp,                  // [16][H][256] f32
    unsigned short* smem)
{
    constexpr int WP = W + 2;
    constexpr int NPX = H * W;
    constexpr int SLOTS = 3 * WL * 16;

    int h = bid % H, b = bid / H;
    int lane = tid & 63, wv = tid >> 6;      // 8 waves
    int g = lane >> 4, l15 = lane & 15;
    int co0 = wv * 32;

    f32x4 acc[2][NF];
#pragma unroll
    for (int m = 0; m < 2; ++m)
#pragma unroll
        for (int n = 0; n < NF; ++n) acc[m][n] = (f32x4)0.0f;

    const unsigned short* ptrow = PT + (size_t)(b * (H + 2) + h) * WP * 256;

    for (int half = 0; half < 2; ++half) {
        if (half) __syncthreads();
        for (int s = tid; s < SLOTS; s += 512) {
            int r = s / (WL * 16);
            int rem = s - r * (WL * 16);
            int x = rem >> 4, cb = rem & 15;
            int xc = x < WP ? x : WP - 1;
            bf16x8 v = *(const bf16x8*)(ptrow + ((size_t)r * WP + xc) * 256 + half * 128 + cb * 8);
            *(bf16x8*)(smem + (((r * WL + x) * 16) + (cb ^ (x & 15))) * 8) = v;
        }
        __syncthreads();

        __builtin_amdgcn_s_setprio(1);
#pragma unroll
        for (int ky = 0; ky < 3; ++ky) {
#pragma unroll
            for (int kx = 0; kx < 3; ++kx) {
#pragma unroll
                for (int cs = 0; cs < 4; ++cs) {
                    int q = (half * 9 + ky * 3 + kx) * 16 + cs * 4 + g;
                    const unsigned short* ap = WT3 + ((size_t)q * 256 + co0 + l15) * 8;
                    bf16x8 a0 = *(const bf16x8*)(ap);
                    bf16x8 a1 = *(const bf16x8*)(ap + 128);
#pragma unroll
                    for (int nf = 0; nf < NF; ++nf) {
                        int xi = nf * 16 + l15 + kx;
                        bf16x8 bv = *(const bf16x8*)(smem +
                            (((ky * WL + xi) * 16) + ((cs * 4 + g) ^ (xi & 15))) * 8);
                        acc[0][nf] = __builtin_amdgcn_mfma_f32_16x16x32_bf16(a0, bv, acc[0][nf], 0, 0, 0);
                        acc[1][nf] = __builtin_amdgcn_mfma_f32_16x16x32_bf16(a1, bv, acc[1][nf], 0, 0, 0);
                    }
                }
            }
        }
        __builtin_amdgcn_s_setprio(0);
    }

    float cb4[2][4];
#pragma unroll
    for (int m = 0; m < 2; ++m)
#pragma unroll
        for (int j = 0; j < 4; ++j)
            cb4[m][j] = cbias[co0 + m * 16 + g * 4 + j];

    float rs[2][4];
#pragma unroll
    for (int m = 0; m < 2; ++m)
#pragma unroll
        for (int j = 0; j < 4; ++j) rs[m][j] = 0.f;

    __syncthreads();   // smem reuse for transpose
    unsigned short* lds_t = smem;   // [W][260] shorts

#pragma unroll
    for (int m = 0; m < 2; ++m) {
#pragma unroll
        for (int nf = 0; nf < NF; ++nf) {
            int px = nf * 16 + l15;
            bool ok = (px < W);
            short4 o;
#pragma unroll
            for (int j = 0; j < 4; ++j) {
                float v = acc[m][nf][j] + cb4[m][j];
                v = v > 0.f ? v : 0.f;
                if (ok) rs[m][j] += v;
                ((short*)&o)[j] = (short)f2bf(v);
            }
            if (ok) *(short4*)(lds_t + px * 260 + co0 + m * 16 + g * 4) = o;
        }
    }
#pragma unroll
    for (int m = 0; m < 2; ++m)
#pragma unroll
        for (int j = 0; j < 4; ++j) {
            float r = rs[m][j];
            r += __shfl_xor(r, 1);
            r += __shfl_xor(r, 2);
            r += __shfl_xor(r, 4);
            r += __shfl_xor(r, 8);
            if (l15 == 0)
                pp[((size_t)b * H + h) * 256 + co0 + m * 16 + g * 4 + j] = r;
        }
    __syncthreads();
    unsigned short* strow = ST + ((size_t)b * NPX + (size_t)h * W) * 256;
    for (int e = tid; e < W * 64; e += 512) {
        int px = e >> 6, c4 = e & 63;
        short4 v = *(const short4*)(lds_t + px * 260 + c4 * 4);
        *(short4*)(strow + (size_t)px * 256 + c4 * 4) = v;
    }
}

// ---------- fused conv (all levels; XCD-chunked swizzle per level segment) ----------
__global__ __launch_bounds__(512) void conv_all_kernel(
    const unsigned short* __restrict__ PT, const unsigned short* __restrict__ WT3,
    const float* __restrict__ cbias, unsigned short* __restrict__ ST,
    float* __restrict__ pp)
{
    __shared__ unsigned short smem[3 * 84 * 128];  // max (L0): 64,512 B
    int bid = blockIdx.x;
    int tid = threadIdx.x;
    if (bid < 1280) {
        conv_worker<80,80,5,84>(xcd_swz(bid, 1280), tid, PT, WT3, cbias, ST, pp, smem);
    } else if (bid < 1920) {
        conv_worker<40,40,3,52>(xcd_swz(bid - 1280, 640), tid, PT + 27541504LL, WT3, cbias,
                                ST + 26214400LL, pp + 327680, smem);
    } else if (bid < 2240) {
        conv_worker<20,20,2,36>(xcd_swz(bid - 1920, 320), tid, PT + 34766848LL, WT3, cbias,
                                ST + 32768000LL, pp + 491520, smem);
    } else {
        conv_worker<10,10,1,20>(xcd_swz(bid - 2240, 160), tid, PT + 36749312LL, WT3, cbias,
                                ST + 34406400LL, pp + 573440, smem);
    }
}

// ---------- fused pool + head stage 1 ----------
__global__ __launch_bounds__(256) void pool_head_kernel(
    const float* __restrict__ pp,
    const float* __restrict__ clsw1, const float* __restrict__ clsb1,
    const float* __restrict__ regw1, const float* __restrict__ regb1,
    const float* __restrict__ lvlw,  const float* __restrict__ lvlb,
    const float* __restrict__ clsfb, const float* __restrict__ regfb,
    float* __restrict__ hb, float* __restrict__ beff)
{
    const int rows_[4] = {80, 40, 20, 10};
    const int base_[4] = {0, 327680, 491520, 573440};
    const float inv_[4] = {1.f / 6400.f, 1.f / 1600.f, 1.f / 400.f, 1.f / 100.f};
    int lvl = blockIdx.x >> 4;
    int b   = blockIdx.x & 15;
    int t   = threadIdx.x;
    __shared__ float pl[256];
    __shared__ float lgl[4];
    __shared__ float attl;

    {
        int rows = rows_[lvl];
        const float* src = pp + base_[lvl] + ((size_t)b * rows) * 256 + t;
        float s = 0.f;
        for (int r = 0; r < rows; ++r) s += src[r * 256];
        pl[t] = s * inv_[lvl];
    }
    __syncthreads();

    float hval = 0.f;
    if (t < 64) {
        float a = clsb1[t];
        const float* wr = clsw1 + t * 256;
        for (int c2 = 0; c2 < 256; ++c2) a = fmaf(pl[c2], wr[c2], a);
        hval = a > 0.f ? a : 0.f;
    } else if (t < 128) {
        int j = t - 64;
        float a = regb1[j];
        const float* wr = regw1 + j * 256;
        for (int c2 = 0; c2 < 256; ++c2) a = fmaf(pl[c2], wr[c2], a);
        hval = a > 0.f ? a : 0.f;
    } else if (t < 132) {
        int j = t - 128;
        float a = lvlb[j];
        const float* wr = lvlw + j * 256;
        for (int c2 = 0; c2 < 256; ++c2) a = fmaf(pl[c2], wr[c2], a);
        lgl[j] = a;
    }
    __syncthreads();
    if (t == 0) {
        float m = fmaxf(fmaxf(lgl[0], lgl[1]), fmaxf(lgl[2], lgl[3]));
        float e0 = expf(lgl[0] - m), e1 = expf(lgl[1] - m);
        float e2 = expf(lgl[2] - m), e3 = expf(lgl[3] - m);
        float se = e0 + e1 + e2 + e3;
        float el = (lvl == 0) ? e0 : (lvl == 1) ? e1 : (lvl == 2) ? e2 : e3;
        attl = el / se;
    }
    __syncthreads();
    float att = attl;

    size_t base = (size_t)(lvl * 16 + b) * 136;
    if (t < 128) hb[base + t] = hval;
    else if (t == 128) hb[base + 128] = att;
    if (t < 84) {
        beff[(lvl * 16 + b) * 84 + t] = att * (t < 80 ? clsfb[t] : regfb[t - 80]);
    }
}

// ---------- head stage 2: weffM[lb][96][256] bf16 (m-major), rows 84..95 zero ----------
__global__ __launch_bounds__(256) void weff2_kernel(
    const float* __restrict__ hb,
    const float* __restrict__ clsw2, const float* __restrict__ clsb2,
    const float* __restrict__ regw2, const float* __restrict__ regb2,
    const float* __restrict__ clsfw, const float* __restrict__ regfw,
    unsigned short* __restrict__ weffM)
{
    int c = blockIdx.x;      // 0..255
    int t = threadIdx.x;
    __shared__ float wlds[84 * 64];
    __shared__ float hcs[64 * 65];
    __shared__ float hrs[64 * 65];
    __shared__ float atts[64];
    __shared__ float cst[84];

    {
        const float4* csrc = (const float4*)(clsw2 + (size_t)c * 80 * 64);
        float4* wd = (float4*)wlds;
        for (int e = t; e < 80 * 16; e += 256) wd[e] = csrc[e];
        const float4* rsrc = (const float4*)(regw2 + (size_t)c * 4 * 64);
        for (int e = t; e < 4 * 16; e += 256) wd[80 * 16 + e] = rsrc[e];
    }
    for (int e = t; e < 64 * 64; e += 256) {
        int lb = e >> 6, j = e & 63;
        hcs[lb * 65 + j] = hb[(size_t)lb * 136 + j];
        hrs[lb * 65 + j] = hb[(size_t)lb * 136 + 64 + j];
    }
    if (t < 64) atts[t] = hb[(size_t)t * 136 + 128];
    if (t < 84) {
        cst[t] = (t < 80) ? (clsb2[(size_t)c * 80 + t] + clsfw[(size_t)t * 256 + c])
                          : (regb2[(size_t)c * 4 + (t - 80)] + regfw[(size_t)(t - 80) * 256 + c]);
    }
    __syncthreads();

    int lb = t & 63;
    int kg0 = t >> 6;
    const float* hc = hcs + lb * 65;
    const float* hr = hrs + lb * 65;
    float att = atts[lb];
    unsigned short* ob = weffM + (size_t)lb * 24576;

    for (int kg = kg0; kg < 21; kg += 4) {
        const float* h = (kg == 20) ? hr : hc;
        const float* wr = wlds + kg * 4 * 64;
        float a0 = 0.f, a1 = 0.f, a2 = 0.f, a3 = 0.f;
#pragma unroll
        for (int j = 0; j < 64; ++j) {
            float hj = h[j];
            a0 = fmaf(hj, wr[j], a0);
            a1 = fmaf(hj, wr[64 + j], a1);
            a2 = fmaf(hj, wr[128 + j], a2);
            a3 = fmaf(hj, wr[192 + j], a3);
        }
        int k = kg * 4;
        ob[(size_t)(k + 0) * 256 + c] = f2bf(att * (cst[k + 0] + a0));
        ob[(size_t)(k + 1) * 256 + c] = f2bf(att * (cst[k + 1] + a1));
        ob[(size_t)(k + 2) * 256 + c] = f2bf(att * (cst[k + 2] + a2));
        ob[(size_t)(k + 3) * 256 + c] = f2bf(att * (cst[k + 3] + a3));
    }
    for (int e = t; e < 64 * 12; e += 256) {
        int lb2 = e / 12, k2 = 84 + (e - lb2 * 12);
        weffM[(size_t)lb2 * 24576 + (size_t)k2 * 256 + c] = 0;
    }
}

// ---------- MFMA epilogue (+ setprio around MFMA cluster) ----------
__global__ __launch_bounds__(512) void epilogue_mfma_kernel(
    const unsigned short* __restrict__ ST, const unsigned short* __restrict__ weffM,
    const float* __restrict__ beff, float* __restrict__ out)
{
    int bid = blockIdx.x;   // 560 blocks
    int lvl, tiles, rem;
    if (bid < 400)      { lvl = 0; tiles = 25; rem = bid; }
    else if (bid < 512) { lvl = 1; tiles = 7;  rem = bid - 400; }
    else if (bid < 544) { lvl = 2; tiles = 2;  rem = bid - 512; }
    else                { lvl = 3; tiles = 1;  rem = bid - 544; }
    const int npx_[4] = {6400, 1600, 400, 100};
    const long long stb_[4] = {0LL, 26214400LL, 32768000LL, 34406400LL};
    const int cb_[4]  = {0, 8192000, 10240000, 10752000};
    const int rb_[4]  = {10880000, 11289600, 11392000, 11417600};
    int npx  = npx_[lvl];
    int tile = rem % tiles;
    int b    = rem / tiles;
    int lb   = lvl * 16 + b;
    int px0  = tile * 256;

    int tid = threadIdx.x;
    int lane = tid & 63, wv = tid >> 6;   // 8 waves
    int g = lane >> 4, l15 = lane & 15;

    __shared__ unsigned short walds[96 * 256];
    __shared__ unsigned short slds[256 * 32];

    const unsigned short* wsrc = weffM + (size_t)lb * 24576;
    for (int e = tid; e < 96 * 32; e += 512) {
        int row = e >> 5, ch = e & 31;
        bf16x8 v = *(const bf16x8*)(wsrc + (size_t)row * 256 + ch * 8);
        int chp = (ch & 16) | ((ch & 15) ^ (row & 15));
        *(bf16x8*)(walds + row * 256 + chp * 8) = v;
    }

    f32x4 acc[6][2];
#pragma unroll
    for (int m = 0; m < 6; ++m) { acc[m][0] = (f32x4)0.0f; acc[m][1] = (f32x4)0.0f; }

    const unsigned short* stB = ST + stb_[lvl] + ((size_t)b * npx + px0) * 256;

    for (int kk = 0; kk < 8; ++kk) {
        __syncthreads();
        for (int pr = tid; pr < 1024; pr += 512) {
            int px = pr >> 2, e = pr & 3;
            bf16x8 v = *(const bf16x8*)(stB + (size_t)px * 256 + kk * 32 + e * 8);
            *(bf16x8*)(slds + px * 32 + ((e ^ ((px >> 1) & 3)) * 8)) = v;
        }
        __syncthreads();

        __builtin_amdgcn_s_setprio(1);
        bf16x8 af[6];
#pragma unroll
        for (int m = 0; m < 6; ++m) {
            int row = m * 16 + l15;
            int chA = kk * 4 + g;
            int chp = (chA & 16) | ((chA & 15) ^ (row & 15));
            af[m] = *(const bf16x8*)(walds + row * 256 + chp * 8);
        }
#pragma unroll
        for (int nn = 0; nn < 2; ++nn) {
            int px = wv * 32 + nn * 16 + l15;
            bf16x8 bf = *(const bf16x8*)(slds + px * 32 + ((g ^ ((px >> 1) & 3)) * 8));
#pragma unroll
            for (int m = 0; m < 6; ++m)
                acc[m][nn] = __builtin_amdgcn_mfma_f32_16x16x32_bf16(af[m], bf, acc[m][nn], 0, 0, 0);
        }
        __builtin_amdgcn_s_setprio(0);
    }

    const float* lbeff = beff + (size_t)lb * 84;
#pragma unroll
    for (int m = 0; m < 6; ++m) {
#pragma unroll
        for (int nn = 0; nn < 2; ++nn) {
            int px = px0 + wv * 32 + nn * 16 + l15;
            if (px >= npx) continue;
#pragma unroll
            for (int j = 0; j < 4; ++j) {
                int k = m * 16 + g * 4 + j;
                if (k >= 84) continue;
                float v = acc[m][nn][j] + lbeff[k];
                float* op;
                if (k < 80) op = out + cb_[lvl] + ((size_t)b * 80 + k) * npx + px;
                else        op = out + rb_[lvl] + ((size_t)b * 4 + (k - 80)) * npx + px;
                *op = v;
            }
        }
    }
}

extern "C" void kernel_launch(void* const* d_in, const int* in_sizes, int n_in,
                              void* d_out, int out_size, void* d_ws, size_t ws_size,
                              hipStream_t stream) {
    (void)in_sizes; (void)n_in; (void)out_size; (void)ws_size;
    const float* feat0  = (const float*)d_in[0];
    const float* feat1  = (const float*)d_in[1];
    const float* feat2  = (const float*)d_in[2];
    const float* feat3  = (const float*)d_in[3];
    const float* conv_w = (const float*)d_in[4];
    const float* conv_b = (const float*)d_in[5];
    const float* clsw1  = (const float*)d_in[6];
    const float* clsb1  = (const float*)d_in[7];
    const float* clsw2  = (const float*)d_in[8];
    const float* clsb2  = (const float*)d_in[9];
    const float* regw1  = (const float*)d_in[10];
    const float* regb1  = (const float*)d_in[11];
    const float* regw2  = (const float*)d_in[12];
    const float* regb2  = (const float*)d_in[13];
    const float* lvlw   = (const float*)d_in[14];
    const float* lvlb   = (const float*)d_in[15];
    const float* clsfw  = (const float*)d_in[16];
    const float* clsfb  = (const float*)d_in[17];
    const float* regfw  = (const float*)d_in[18];
    const float* regfb  = (const float*)d_in[19];

    char* ws = (char*)d_ws;
    unsigned short* WT3   = (unsigned short*)(ws + OFFB_WT3);
    unsigned short* PT    = (unsigned short*)(ws + OFFB_PT);
    unsigned short* weffM = (unsigned short*)(ws + OFFB_WEFFM);
    unsigned short* ST    = (unsigned short*)(ws + OFFB_ST);
    float*          pp    = (float*)(ws + OFFB_PP);
    float*          beff  = (float*)(ws + OFFB_BEFF);
    float*          hb    = (float*)(ws + OFFB_HB);
    float* out = (float*)d_out;

    // fused prep_w + pad_transpose: 256 + 1312 + 672 + 352 + 192 = 2784 blocks
    hipLaunchKernelGGL(prep_pad_kernel, dim3(2784), dim3(256), 0, stream,
                       conv_w, feat0, feat1, feat2, feat3, WT3, PT);

    // fused conv: 1280 + 640 + 320 + 160 = 2400 blocks (r14 config + XCD swizzle)
    hipLaunchKernelGGL(conv_all_kernel, dim3(2400), dim3(512), 0, stream,
                       PT, WT3, conv_b, ST, pp);

    hipLaunchKernelGGL(pool_head_kernel, dim3(64), dim3(256), 0, stream, pp,
                       clsw1, clsb1, regw1, regb1, lvlw, lvlb, clsfb, regfb, hb, beff);
    hipLaunchKernelGGL(weff2_kernel, dim3(256), dim3(256), 0, stream, hb,
                       clsw2, clsb2, regw2, regb2, clsfw, regfw, weffM);
    hipLaunchKernelGGL(epilogue_mfma_kernel, dim3(560), dim3(512), 0, stream, ST, weffM, beff, out);
}

// Round 18
// 303.355 us; speedup vs baseline: 1.3432x; 1.0171x over previous
//
#include <hip/hip_runtime.h>
#include <math.h>

typedef __attribute__((ext_vector_type(8))) short bf16x8;
typedef __attribute__((ext_vector_type(4))) float f32x4;
typedef unsigned int uint32;

// ---- workspace layout (BYTES) ----
#define OFFB_WT3   0LL           // 1,179,648   : WT3[288][256][8] bf16
#define OFFB_PT    1179648LL     // 74,678,272  : PT padded-transposed feats bf16
#define OFFB_WEFFM 1179648LL     // 3,145,728   : weffM[64][96][256] bf16 (ALIASES PT; written after conv)
#define OFFB_ST    75857920LL    // 69,632,000  : S^T [b][px][c] bf16 per level
#define OFFB_PP    145489920LL   // 2,457,600   : pp[lvl][b][H][256] f32
#define OFFB_BEFF  150470656LL   // 21,504      : beff f32
#define OFFB_HB    150492160LL   // 34,816      : hb[64][136] f32
// end = 150,526,976 bytes (<= 150,983,680 proven in round 1)

// PT element bases: PT0=0  PT1=27,541,504  PT2=34,766,848  PT3=36,749,312
// ST element bases: ST0=0  ST1=26,214,400  ST2=32,768,000  ST3=34,406,400
// pp float bases:   pp0=0 [16][80][256]  pp1=327,680  pp2=491,520  pp3=573,440

__device__ inline unsigned short f2bf(float f) {
    uint32 u = __float_as_uint(f);
    uint32 r = (u + 0x7fffu + ((u >> 16) & 1u)) >> 16;
    return (unsigned short)r;
}

// XCD-chunked bijective swizzle (segment size N must be %8==0)
__device__ inline int xcd_swz(int bid, int N) {
    return (bid & 7) * (N >> 3) + (bid >> 3);
}

// ---------- prep_w worker: WT3[q][co][j], q=(half*9+tap)*16 + (ci&127)>>3 ----------
__device__ void prep_w_worker(int co, int ci, const float* __restrict__ w,
                              unsigned short* __restrict__ WT3) {
    int half = ci >> 7, cc = ci & 127, c8 = cc >> 3, j = cc & 7;
    const float* src = w + ((size_t)co * 256 + ci) * 9;
#pragma unroll
    for (int tap = 0; tap < 9; ++tap) {
        int q = (half * 9 + tap) * 16 + c8;
        WT3[((size_t)q * 256 + co) * 8 + j] = f2bf(src[tap]);
    }
}

// ---------- pad worker (vectorized): PT[b][y][x][ci] bf16, zero border ----------
// lds layout: [256][84] shorts (stride 84 => 8B-aligned short4 rows)
template<int H, int W>
__device__ void pad_worker(int bid, int t, const float* __restrict__ feat,
                           unsigned short* __restrict__ PT, unsigned short* lds) {
    constexpr int WP = W + 2;
    int y = bid % (H + 2), b = bid / (H + 2);
    unsigned short* dst = PT + ((size_t)(b * (H + 2) + y)) * WP * 256;
    if (y == 0 || y == H + 1) {
        short4 z; z.x = 0; z.y = 0; z.z = 0; z.w = 0;
        for (int e = t; e < WP * 64; e += 256) *(short4*)(dst + e * 4) = z;
        return;
    }
    const float* src = feat + ((size_t)b * 256) * (H * W) + (size_t)(y - 1) * W;
    if constexpr (W % 4 == 0) {
        constexpr int NQ = W / 4;
        for (int e = t; e < 256 * NQ; e += 256) {
            int ci = e / NQ, xq = e - ci * NQ;
            float4 v = *(const float4*)(src + (size_t)ci * H * W + xq * 4);
            short4 o;
            o.x = (short)f2bf(v.x); o.y = (short)f2bf(v.y);
            o.z = (short)f2bf(v.z); o.w = (short)f2bf(v.w);
            *(short4*)(lds + ci * 84 + xq * 4) = o;
        }
    } else {
        for (int e = t; e < 256 * W; e += 256) {
            int ci = e / W, x = e - ci * W;
            lds[ci * 84 + x] = f2bf(src[(size_t)ci * H * W + x]);
        }
    }
    __syncthreads();
    for (int e = t; e < WP * 64; e += 256) {
        int x = e >> 6, c4 = e & 63;
        short4 o;
        if (x == 0 || x == W + 1) {
            o.x = 0; o.y = 0; o.z = 0; o.w = 0;
        } else {
            o.x = (short)lds[(c4 * 4 + 0) * 84 + x - 1];
            o.y = (short)lds[(c4 * 4 + 1) * 84 + x - 1];
            o.z = (short)lds[(c4 * 4 + 2) * 84 + x - 1];
            o.w = (short)lds[(c4 * 4 + 3) * 84 + x - 1];
        }
        *(short4*)(dst + x * 256 + c4 * 4) = o;
    }
}

// ---------- fused prep_w + pad_transpose (all levels) ----------
__global__ __launch_bounds__(256) void prep_pad_kernel(
    const float* __restrict__ conv_w,
    const float* __restrict__ feat0, const float* __restrict__ feat1,
    const float* __restrict__ feat2, const float* __restrict__ feat3,
    unsigned short* __restrict__ WT3, unsigned short* __restrict__ PT)
{
    __shared__ unsigned short lds[256 * 84];   // 43,008 B
    int bid = blockIdx.x;
    int t = threadIdx.x;
    if (bid < 256)        { prep_w_worker(bid, t, conv_w, WT3); }
    else if (bid < 1568)  { pad_worker<80,80>(bid - 256,  t, feat0, PT,              lds); }
    else if (bid < 2240)  { pad_worker<40,40>(bid - 1568, t, feat1, PT + 27541504LL, lds); }
    else if (bid < 2592)  { pad_worker<20,20>(bid - 2240, t, feat2, PT + 34766848LL, lds); }
    else                  { pad_worker<10,10>(bid - 2592, t, feat3, PT + 36749312LL, lds); }
}

// ---------- conv worker (r14 body + setprio around MFMA phase) ----------
template<int H, int W, int NF, int WL>
__device__ void conv_worker(int bid, int tid,
    const unsigned short* __restrict__ PT,   // [16][H+2][W+2][256]
    const unsigned short* __restrict__ WT3,  // [288][256][8]
    const float* __restrict__ cbias,
    unsigned short* __restrict__ ST,         // [16][H*W][256] bf16 (px-major)
    float* __restrict__ pp,                  // [16][H][256] f32
    unsigned short* smem)
{
    constexpr int WP = W + 2;
    constexpr int NPX = H * W;
    constexpr int SLOTS = 3 * WL * 16;

    int h = bid % H, b = bid / H;
    int lane = tid & 63, wv = tid >> 6;      // 8 waves
    int g = lane >> 4, l15 = lane & 15;
    int co0 = wv * 32;

    f32x4 acc[2][NF];
#pragma unroll
    for (int m = 0; m < 2; ++m)
#pragma unroll
        for (int n = 0; n < NF; ++n) acc[m][n] = (f32x4)0.0f;

    const unsigned short* ptrow = PT + (size_t)(b * (H + 2) + h) * WP * 256;

    for (int half = 0; half < 2; ++half) {
        if (half) __syncthreads();
        for (int s = tid; s < SLOTS; s += 512) {
            int r = s / (WL * 16);
            int rem = s - r * (WL * 16);
            int x = rem >> 4, cb = rem & 15;
            int xc = x < WP ? x : WP - 1;
            bf16x8 v = *(const bf16x8*)(ptrow + ((size_t)r * WP + xc) * 256 + half * 128 + cb * 8);
            *(bf16x8*)(smem + (((r * WL + x) * 16) + (cb ^ (x & 15))) * 8) = v;
        }
        __syncthreads();

        __builtin_amdgcn_s_setprio(1);
#pragma unroll
        for (int ky = 0; ky < 3; ++ky) {
#pragma unroll
            for (int kx = 0; kx < 3; ++kx) {
#pragma unroll
                for (int cs = 0; cs < 4; ++cs) {
                    int q = (half * 9 + ky * 3 + kx) * 16 + cs * 4 + g;
                    const unsigned short* ap = WT3 + ((size_t)q * 256 + co0 + l15) * 8;
                    bf16x8 a0 = *(const bf16x8*)(ap);
                    bf16x8 a1 = *(const bf16x8*)(ap + 128);
#pragma unroll
                    for (int nf = 0; nf < NF; ++nf) {
                        int xi = nf * 16 + l15 + kx;
                        bf16x8 bv = *(const bf16x8*)(smem +
                            (((ky * WL + xi) * 16) + ((cs * 4 + g) ^ (xi & 15))) * 8);
                        acc[0][nf] = __builtin_amdgcn_mfma_f32_16x16x32_bf16(a0, bv, acc[0][nf], 0, 0, 0);
                        acc[1][nf] = __builtin_amdgcn_mfma_f32_16x16x32_bf16(a1, bv, acc[1][nf], 0, 0, 0);
                    }
                }
            }
        }
        __builtin_amdgcn_s_setprio(0);
    }

    float cb4[2][4];
#pragma unroll
    for (int m = 0; m < 2; ++m)
#pragma unroll
        for (int j = 0; j < 4; ++j)
            cb4[m][j] = cbias[co0 + m * 16 + g * 4 + j];

    float rs[2][4];
#pragma unroll
    for (int m = 0; m < 2; ++m)
#pragma unroll
        for (int j = 0; j < 4; ++j) rs[m][j] = 0.f;

    __syncthreads();   // smem reuse for transpose
    unsigned short* lds_t = smem;   // [W][260] shorts

#pragma unroll
    for (int m = 0; m < 2; ++m) {
#pragma unroll
        for (int nf = 0; nf < NF; ++nf) {
            int px = nf * 16 + l15;
            bool ok = (px < W);
            short4 o;
#pragma unroll
            for (int j = 0; j < 4; ++j) {
                float v = acc[m][nf][j] + cb4[m][j];
                v = v > 0.f ? v : 0.f;
                if (ok) rs[m][j] += v;
                ((short*)&o)[j] = (short)f2bf(v);
            }
            if (ok) *(short4*)(lds_t + px * 260 + co0 + m * 16 + g * 4) = o;
        }
    }
#pragma unroll
    for (int m = 0; m < 2; ++m)
#pragma unroll
        for (int j = 0; j < 4; ++j) {
            float r = rs[m][j];
            r += __shfl_xor(r, 1);
            r += __shfl_xor(r, 2);
            r += __shfl_xor(r, 4);
            r += __shfl_xor(r, 8);
            if (l15 == 0)
                pp[((size_t)b * H + h) * 256 + co0 + m * 16 + g * 4 + j] = r;
        }
    __syncthreads();
    unsigned short* strow = ST + ((size_t)b * NPX + (size_t)h * W) * 256;
    for (int e = tid; e < W * 64; e += 512) {
        int px = e >> 6, c4 = e & 63;
        short4 v = *(const short4*)(lds_t + px * 260 + c4 * 4);
        *(short4*)(strow + (size_t)px * 256 + c4 * 4) = v;
    }
}

// ---------- fused conv (all levels; XCD-chunked swizzle per level segment) ----------
__global__ __launch_bounds__(512) void conv_all_kernel(
    const unsigned short* __restrict__ PT, const unsigned short* __restrict__ WT3,
    const float* __restrict__ cbias, unsigned short* __restrict__ ST,
    float* __restrict__ pp)
{
    __shared__ unsigned short smem[3 * 84 * 128];  // max (L0): 64,512 B
    int bid = blockIdx.x;
    int tid = threadIdx.x;
    if (bid < 1280) {
        conv_worker<80,80,5,84>(xcd_swz(bid, 1280), tid, PT, WT3, cbias, ST, pp, smem);
    } else if (bid < 1920) {
        conv_worker<40,40,3,52>(xcd_swz(bid - 1280, 640), tid, PT + 27541504LL, WT3, cbias,
                                ST + 26214400LL, pp + 327680, smem);
    } else if (bid < 2240) {
        conv_worker<20,20,2,36>(xcd_swz(bid - 1920, 320), tid, PT + 34766848LL, WT3, cbias,
                                ST + 32768000LL, pp + 491520, smem);
    } else {
        conv_worker<10,10,1,20>(xcd_swz(bid - 2240, 160), tid, PT + 36749312LL, WT3, cbias,
                                ST + 34406400LL, pp + 573440, smem);
    }
}

// ---------- fused pool + head stage 1 ----------
__global__ __launch_bounds__(256) void pool_head_kernel(
    const float* __restrict__ pp,
    const float* __restrict__ clsw1, const float* __restrict__ clsb1,
    const float* __restrict__ regw1, const float* __restrict__ regb1,
    const float* __restrict__ lvlw,  const float* __restrict__ lvlb,
    const float* __restrict__ clsfb, const float* __restrict__ regfb,
    float* __restrict__ hb, float* __restrict__ beff)
{
    const int rows_[4] = {80, 40, 20, 10};
    const int base_[4] = {0, 327680, 491520, 573440};
    const float inv_[4] = {1.f / 6400.f, 1.f / 1600.f, 1.f / 400.f, 1.f / 100.f};
    int lvl = blockIdx.x >> 4;
    int b   = blockIdx.x & 15;
    int t   = threadIdx.x;
    __shared__ float pl[256];
    __shared__ float lgl[4];
    __shared__ float attl;

    {
        int rows = rows_[lvl];
        const float* src = pp + base_[lvl] + ((size_t)b * rows) * 256 + t;
        float s = 0.f;
        for (int r = 0; r < rows; ++r) s += src[r * 256];
        pl[t] = s * inv_[lvl];
    }
    __syncthreads();

    float hval = 0.f;
    if (t < 64) {
        float a = clsb1[t];
        const float* wr = clsw1 + t * 256;
        for (int c2 = 0; c2 < 256; ++c2) a = fmaf(pl[c2], wr[c2], a);
        hval = a > 0.f ? a : 0.f;
    } else if (t < 128) {
        int j = t - 64;
        float a = regb1[j];
        const float* wr = regw1 + j * 256;
        for (int c2 = 0; c2 < 256; ++c2) a = fmaf(pl[c2], wr[c2], a);
        hval = a > 0.f ? a : 0.f;
    } else if (t < 132) {
        int j = t - 128;
        float a = lvlb[j];
        const float* wr = lvlw + j * 256;
        for (int c2 = 0; c2 < 256; ++c2) a = fmaf(pl[c2], wr[c2], a);
        lgl[j] = a;
    }
    __syncthreads();
    if (t == 0) {
        float m = fmaxf(fmaxf(lgl[0], lgl[1]), fmaxf(lgl[2], lgl[3]));
        float e0 = expf(lgl[0] - m), e1 = expf(lgl[1] - m);
        float e2 = expf(lgl[2] - m), e3 = expf(lgl[3] - m);
        float se = e0 + e1 + e2 + e3;
        float el = (lvl == 0) ? e0 : (lvl == 1) ? e1 : (lvl == 2) ? e2 : e3;
        attl = el / se;
    }
    __syncthreads();
    float att = attl;

    size_t base = (size_t)(lvl * 16 + b) * 136;
    if (t < 128) hb[base + t] = hval;
    else if (t == 128) hb[base + 128] = att;
    if (t < 84) {
        beff[(lvl * 16 + b) * 84 + t] = att * (t < 80 ? clsfb[t] : regfb[t - 80]);
    }
}

// ---------- head stage 2: weffM[lb][96][256] bf16 (m-major), rows 84..95 zero ----------
__global__ __launch_bounds__(256) void weff2_kernel(
    const float* __restrict__ hb,
    const float* __restrict__ clsw2, const float* __restrict__ clsb2,
    const float* __restrict__ regw2, const float* __restrict__ regb2,
    const float* __restrict__ clsfw, const float* __restrict__ regfw,
    unsigned short* __restrict__ weffM)
{
    int c = blockIdx.x;      // 0..255
    int t = threadIdx.x;
    __shared__ float wlds[84 * 64];
    __shared__ float hcs[64 * 65];
    __shared__ float hrs[64 * 65];
    __shared__ float atts[64];
    __shared__ float cst[84];

    {
        const float4* csrc = (const float4*)(clsw2 + (size_t)c * 80 * 64);
        float4* wd = (float4*)wlds;
        for (int e = t; e < 80 * 16; e += 256) wd[e] = csrc[e];
        const float4* rsrc = (const float4*)(regw2 + (size_t)c * 4 * 64);
        for (int e = t; e < 4 * 16; e += 256) wd[80 * 16 + e] = rsrc[e];
    }
    for (int e = t; e < 64 * 64; e += 256) {
        int lb = e >> 6, j = e & 63;
        hcs[lb * 65 + j] = hb[(size_t)lb * 136 + j];
        hrs[lb * 65 + j] = hb[(size_t)lb * 136 + 64 + j];
    }
    if (t < 64) atts[t] = hb[(size_t)t * 136 + 128];
    if (t < 84) {
        cst[t] = (t < 80) ? (clsb2[(size_t)c * 80 + t] + clsfw[(size_t)t * 256 + c])
                          : (regb2[(size_t)c * 4 + (t - 80)] + regfw[(size_t)(t - 80) * 256 + c]);
    }
    __syncthreads();

    int lb = t & 63;
    int kg0 = t >> 6;
    const float* hc = hcs + lb * 65;
    const float* hr = hrs + lb * 65;
    float att = atts[lb];
    unsigned short* ob = weffM + (size_t)lb * 24576;

    for (int kg = kg0; kg < 21; kg += 4) {
        const float* h = (kg == 20) ? hr : hc;
        const float* wr = wlds + kg * 4 * 64;
        float a0 = 0.f, a1 = 0.f, a2 = 0.f, a3 = 0.f;
#pragma unroll
        for (int j = 0; j < 64; ++j) {
            float hj = h[j];
            a0 = fmaf(hj, wr[j], a0);
            a1 = fmaf(hj, wr[64 + j], a1);
            a2 = fmaf(hj, wr[128 + j], a2);
            a3 = fmaf(hj, wr[192 + j], a3);
        }
        int k = kg * 4;
        ob[(size_t)(k + 0) * 256 + c] = f2bf(att * (cst[k + 0] + a0));
        ob[(size_t)(k + 1) * 256 + c] = f2bf(att * (cst[k + 1] + a1));
        ob[(size_t)(k + 2) * 256 + c] = f2bf(att * (cst[k + 2] + a2));
        ob[(size_t)(k + 3) * 256 + c] = f2bf(att * (cst[k + 3] + a3));
    }
    for (int e = t; e < 64 * 12; e += 256) {
        int lb2 = e / 12, k2 = 84 + (e - lb2 * 12);
        weffM[(size_t)lb2 * 24576 + (size_t)k2 * 256 + c] = 0;
    }
}

// ---------- MFMA epilogue (+ setprio around MFMA cluster) ----------
__global__ __launch_bounds__(512) void epilogue_mfma_kernel(
    const unsigned short* __restrict__ ST, const unsigned short* __restrict__ weffM,
    const float* __restrict__ beff, float* __restrict__ out)
{
    int bid = blockIdx.x;   // 560 blocks
    int lvl, tiles, rem;
    if (bid < 400)      { lvl = 0; tiles = 25; rem = bid; }
    else if (bid < 512) { lvl = 1; tiles = 7;  rem = bid - 400; }
    else if (bid < 544) { lvl = 2; tiles = 2;  rem = bid - 512; }
    else                { lvl = 3; tiles = 1;  rem = bid - 544; }
    const int npx_[4] = {6400, 1600, 400, 100};
    const long long stb_[4] = {0LL, 26214400LL, 32768000LL, 34406400LL};
    const int cb_[4]  = {0, 8192000, 10240000, 10752000};
    const int rb_[4]  = {10880000, 11289600, 11392000, 11417600};
    int npx  = npx_[lvl];
    int tile = rem % tiles;
    int b    = rem / tiles;
    int lb   = lvl * 16 + b;
    int px0  = tile * 256;

    int tid = threadIdx.x;
    int lane = tid & 63, wv = tid >> 6;   // 8 waves
    int g = lane >> 4, l15 = lane & 15;

    __shared__ unsigned short walds[96 * 256];
    __shared__ unsigned short slds[256 * 32];

    const unsigned short* wsrc = weffM + (size_t)lb * 24576;
    for (int e = tid; e < 96 * 32; e += 512) {
        int row = e >> 5, ch = e & 31;
        bf16x8 v = *(const bf16x8*)(wsrc + (size_t)row * 256 + ch * 8);
        int chp = (ch & 16) | ((ch & 15) ^ (row & 15));
        *(bf16x8*)(walds + row * 256 + chp * 8) = v;
    }

    f32x4 acc[6][2];
#pragma unroll
    for (int m = 0; m < 6; ++m) { acc[m][0] = (f32x4)0.0f; acc[m][1] = (f32x4)0.0f; }

    const unsigned short* stB = ST + stb_[lvl] + ((size_t)b * npx + px0) * 256;

    for (int kk = 0; kk < 8; ++kk) {
        __syncthreads();
        for (int pr = tid; pr < 1024; pr += 512) {
            int px = pr >> 2, e = pr & 3;
            bf16x8 v = *(const bf16x8*)(stB + (size_t)px * 256 + kk * 32 + e * 8);
            *(bf16x8*)(slds + px * 32 + ((e ^ ((px >> 1) & 3)) * 8)) = v;
        }
        __syncthreads();

        __builtin_amdgcn_s_setprio(1);
        bf16x8 af[6];
#pragma unroll
        for (int m = 0; m < 6; ++m) {
            int row = m * 16 + l15;
            int chA = kk * 4 + g;
            int chp = (chA & 16) | ((chA & 15) ^ (row & 15));
            af[m] = *(const bf16x8*)(walds + row * 256 + chp * 8);
        }
#pragma unroll
        for (int nn = 0; nn < 2; ++nn) {
            int px = wv * 32 + nn * 16 + l15;
            bf16x8 bf = *(const bf16x8*)(slds + px * 32 + ((g ^ ((px >> 1) & 3)) * 8));
#pragma unroll
            for (int m = 0; m < 6; ++m)
                acc[m][nn] = __builtin_amdgcn_mfma_f32_16x16x32_bf16(af[m], bf, acc[m][nn], 0, 0, 0);
        }
        __builtin_amdgcn_s_setprio(0);
    }

    const float* lbeff = beff + (size_t)lb * 84;
#pragma unroll
    for (int m = 0; m < 6; ++m) {
#pragma unroll
        for (int nn = 0; nn < 2; ++nn) {
            int px = px0 + wv * 32 + nn * 16 + l15;
            if (px >= npx) continue;
#pragma unroll
            for (int j = 0; j < 4; ++j) {
                int k = m * 16 + g * 4 + j;
                if (k >= 84) continue;
                float v = acc[m][nn][j] + lbeff[k];
                float* op;
                if (k < 80) op = out + cb_[lvl] + ((size_t)b * 80 + k) * npx + px;
                else        op = out + rb_[lvl] + ((size_t)b * 4 + (k - 80)) * npx + px;
                *op = v;
            }
        }
    }
}

extern "C" void kernel_launch(void* const* d_in, const int* in_sizes, int n_in,
                              void* d_out, int out_size, void* d_ws, size_t ws_size,
                              hipStream_t stream) {
    (void)in_sizes; (void)n_in; (void)out_size; (void)ws_size;
    const float* feat0  = (const float*)d_in[0];
    const float* feat1  = (const float*)d_in[1];
    const float* feat2  = (const float*)d_in[2];
    const float* feat3  = (const float*)d_in[3];
    const float* conv_w = (const float*)d_in[4];
    const float* conv_b = (const float*)d_in[5];
    const float* clsw1  = (const float*)d_in[6];
    const float* clsb1  = (const float*)d_in[7];
    const float* clsw2  = (const float*)d_in[8];
    const float* clsb2  = (const float*)d_in[9];
    const float* regw1  = (const float*)d_in[10];
    const float* regb1  = (const float*)d_in[11];
    const float* regw2  = (const float*)d_in[12];
    const float* regb2  = (const float*)d_in[13];
    const float* lvlw   = (const float*)d_in[14];
    const float* lvlb   = (const float*)d_in[15];
    const float* clsfw  = (const float*)d_in[16];
    const float* clsfb  = (const float*)d_in[17];
    const float* regfw  = (const float*)d_in[18];
    const float* regfb  = (const float*)d_in[19];

    char* ws = (char*)d_ws;
    unsigned short* WT3   = (unsigned short*)(ws + OFFB_WT3);
    unsigned short* PT    = (unsigned short*)(ws + OFFB_PT);
    unsigned short* weffM = (unsigned short*)(ws + OFFB_WEFFM);
    unsigned short* ST    = (unsigned short*)(ws + OFFB_ST);
    float*          pp    = (float*)(ws + OFFB_PP);
    float*          beff  = (float*)(ws + OFFB_BEFF);
    float*          hb    = (float*)(ws + OFFB_HB);
    float* out = (float*)d_out;

    // fused prep_w + pad_transpose: 256 + 1312 + 672 + 352 + 192 = 2784 blocks
    hipLaunchKernelGGL(prep_pad_kernel, dim3(2784), dim3(256), 0, stream,
                       conv_w, feat0, feat1, feat2, feat3, WT3, PT);

    // fused conv: 1280 + 640 + 320 + 160 = 2400 blocks (r14 config + XCD swizzle)
    hipLaunchKernelGGL(conv_all_kernel, dim3(2400), dim3(512), 0, stream,
                       PT, WT3, conv_b, ST, pp);

    hipLaunchKernelGGL(pool_head_kernel, dim3(64), dim3(256), 0, stream, pp,
                       clsw1, clsb1, regw1, regb1, lvlw, lvlb, clsfb, regfb, hb, beff);
    hipLaunchKernelGGL(weff2_kernel, dim3(256), dim3(256), 0, stream, hb,
                       clsw2, clsb2, regw2, regb2, clsfw, regfw, weffM);
    hipLaunchKernelGGL(epilogue_mfma_kernel, dim3(560), dim3(512), 0, stream, ST, weffM, beff, out);
}